// Round 10
// baseline (154.649 us; speedup 1.0000x reference)
//
#include <hip/hip_runtime.h>
#include <hip/hip_bf16.h>
#include <math.h>

// Deformable DETR multi-scale deformable attention — MI355X (gfx950)
// B=2, Lq=Lv=13294, D=256, H=8, HD=32, L=4, P=4
// Levels (square): 100,50,25,13  starts {0,10000,12500,13125}

namespace {
constexpr int LQ    = 13294;
constexpr int LV    = 13294;
constexpr int NROWS = 2 * LQ;   // 26588
}

typedef __attribute__((ext_vector_type(8))) short short8;   // 8 x bf16
typedef __attribute__((ext_vector_type(4))) float f32x4;    // MFMA accumulator

__device__ inline float bf2f(unsigned u16) {
    union { unsigned u; float f; } c; c.u = u16 << 16; return c.f;
}
__device__ inline unsigned short f2bf(float f) {
    __hip_bfloat16 h = __float2bfloat16(f);
    return *reinterpret_cast<unsigned short*>(&h);
}

// ---------------------------------------------------------------------------
// Weight prep, fragment-major: WTf[ctile][kc][lane][8] bf16 over the
// concatenated [Wv^T|Woff^T|Wattn^T|Wout^T] (896 cols = 56 ctiles).
// ---------------------------------------------------------------------------
__global__ __launch_bounds__(256) void prep_weights(
    const float* __restrict__ Wv, const float* __restrict__ Woff,
    const float* __restrict__ Wattn, const float* __restrict__ Wout,
    __hip_bfloat16* __restrict__ WTf)
{
    const int c = blockIdx.x, k = threadIdx.x;
    float v;
    if (c < 256)      v = Wv[k * 256 + c];
    else if (c < 512) v = Woff[k * 256 + (c - 256)];
    else if (c < 640) v = Wattn[k * 128 + (c - 512)];
    else              v = Wout[k * 256 + (c - 640)];
    const int lane = (c & 15) | (((k >> 3) & 3) << 4);
    const size_t dst = ((size_t)((c >> 4) * 8 + (k >> 5)) * 64 + lane) * 8 + (k & 7);
    WTf[dst] = __float2bfloat16(v);
}

// ---------------------------------------------------------------------------
// value / query fp32 -> bf16 row-major (8 elems/thread), y selects tensor.
// GUARDED: grid overshoots by half a block; without the guard the tail
// spills into qbf / WTf (R9's correctness failure).
// ---------------------------------------------------------------------------
__global__ __launch_bounds__(256) void conv_bf16(
    const float* __restrict__ value, const float* __restrict__ query,
    __hip_bfloat16* __restrict__ vbf, __hip_bfloat16* __restrict__ qbf)
{
    constexpr size_t NV = (size_t)NROWS * 256;
    const size_t e = ((size_t)blockIdx.x * 256 + threadIdx.x) * 8;
    if (e >= NV) return;
    const float* src = (blockIdx.y == 0) ? value + e : query + e;
    __hip_bfloat16* dst = (blockIdx.y == 0) ? vbf + e : qbf + e;
    const float4 a = *(const float4*)src;
    const float4 b = *(const float4*)(src + 4);
    union { unsigned short us[8]; uint4 v; } o;
    o.us[0] = f2bf(a.x); o.us[1] = f2bf(a.y); o.us[2] = f2bf(a.z); o.us[3] = f2bf(a.w);
    o.us[4] = f2bf(b.x); o.us[5] = f2bf(b.y); o.us[6] = f2bf(b.z); o.us[7] = f2bf(b.w);
    *(uint4*)dst = o.v;
}

// ---------------------------------------------------------------------------
// Direct GEMM: no LDS, no barriers. Wave = one 16-row tile x full N-slice.
// A: bf16 row-major (per-lane 16B load = 16x64B segments, same line count as
//    coalesced). B: fragment-major WTf (L2-resident, coalesced 1KB/load).
// Per wave: 8 A-loads + 8*NTILES B-loads + 8*NTILES MFMA, fully independent
// waves -> latency hidden by TLP instead of the old stage->barrier serial.
// OUTMODE 0: fp32 Y[rr*ldY+coloff+col] | 1: bf16 same | 2: bf16 head-major
// ---------------------------------------------------------------------------
template<int NTILES, int OUTMODE>
__device__ __forceinline__ void gemm_direct_core(
    const __hip_bfloat16* __restrict__ X,
    const __hip_bfloat16* __restrict__ WTf, int ct0,
    const float* __restrict__ bias, void* __restrict__ Yv,
    int ldY, int coloff, int M, int rt)
{
    const int lane = threadIdx.x & 63;
    const int r16  = lane & 15;
    const int koff = (lane >> 4) * 8;
    int rowA = rt * 16 + r16;
    if (rowA >= M) rowA = M - 1;
    const __hip_bfloat16* ap = X + (size_t)rowA * 256 + koff;

    short8 a[8];
    #pragma unroll
    for (int kc = 0; kc < 8; ++kc)
        a[kc] = *(const short8*)(ap + kc * 32);

    f32x4 acc[NTILES];
    #pragma unroll
    for (int nt = 0; nt < NTILES; ++nt)
        #pragma unroll
        for (int j = 0; j < 4; ++j) acc[nt][j] = 0.f;

    const __hip_bfloat16* bp = WTf + ((size_t)ct0 * 8 * 64 + lane) * 8;
    #pragma unroll
    for (int kc = 0; kc < 8; ++kc) {
        #pragma unroll
        for (int nt = 0; nt < NTILES; ++nt) {
            const short8 bfr = *(const short8*)(bp + (size_t)(nt * 8 + kc) * 512);
            acc[nt] = __builtin_amdgcn_mfma_f32_16x16x32_bf16(a[kc], bfr, acc[nt], 0, 0, 0);
        }
    }

    const int orow = (lane >> 4) * 4;
    #pragma unroll
    for (int nt = 0; nt < NTILES; ++nt) {
        const int col = nt * 16 + r16;
        const float bb = bias[col];
        #pragma unroll
        for (int j = 0; j < 4; ++j) {
            const int rr = rt * 16 + orow + j;
            if (rr < M) {
                const float v = acc[nt][j] + bb;
                if (OUTMODE == 0) {
                    ((float*)Yv)[(size_t)rr * ldY + coloff + col] = v;
                } else if (OUTMODE == 1) {
                    ((__hip_bfloat16*)Yv)[(size_t)rr * ldY + coloff + col] =
                        __float2bfloat16(v);
                } else {
                    const int b  = (rr >= LQ) ? 1 : 0;
                    const int lv = rr - b * LQ;
                    const int h  = col >> 5, cc = col & 31;
                    ((__hip_bfloat16*)Yv)[(((size_t)(b * 8 + h)) * LV + lv) * 32 + cc] =
                        __float2bfloat16(v);
                }
            }
        }
    }
}

// y=0: value->vhm (N=256) | y=1: query->offsets (N=256) | y=2: query->logits (N=128)
__global__ __launch_bounds__(256, 3) void gemm_vq(
    const __hip_bfloat16* __restrict__ vbf, const __hip_bfloat16* __restrict__ qbf,
    const __hip_bfloat16* __restrict__ WTf,
    const float* __restrict__ bv, const float* __restrict__ boff,
    const float* __restrict__ battn,
    __hip_bfloat16* __restrict__ vhm, __hip_bfloat16* __restrict__ offlog, int M)
{
    const int rt = blockIdx.x * 4 + (threadIdx.x >> 6);
    if (blockIdx.y == 0)
        gemm_direct_core<16, 2>(vbf, WTf, 0,  bv,    vhm,    0,   0,   M, rt);
    else if (blockIdx.y == 1)
        gemm_direct_core<16, 1>(qbf, WTf, 16, boff,  offlog, 384, 0,   M, rt);
    else
        gemm_direct_core<8,  1>(qbf, WTf, 32, battn, offlog, 384, 256, M, rt);
}

__global__ __launch_bounds__(256, 3) void gemm_out_k(
    const __hip_bfloat16* __restrict__ sampled, const __hip_bfloat16* __restrict__ WTf,
    const float* __restrict__ bout, float* __restrict__ out, int M)
{
    const int rt = blockIdx.x * 4 + (threadIdx.x >> 6);
    gemm_direct_core<16, 0>(sampled, WTf, 40, bout, out, 256, 0, M, rt);
}

// ---------------------------------------------------------------------------
// ms_sample v7 (unchanged, 62.4 µs measured): 4 rows x all heads per block,
// 4-sample batched gathers.
// ---------------------------------------------------------------------------
__global__ __launch_bounds__(256) void ms_sample(
    const __hip_bfloat16* __restrict__ vhm, const __hip_bfloat16* __restrict__ offlog,
    const float* __restrict__ refpts, __hip_bfloat16* __restrict__ sampled)
{
    __shared__ char params[4][16][304];

    const int t    = threadIdx.x;
    const int row0 = blockIdx.x * 4;

    // ---------------- phase 1 ----------------
    #pragma unroll
    for (int it = 0; it < 2; ++it) {
        const int sid = it * 256 + t;
        const int rl  = sid >> 7;
        const int h   = (sid >> 4) & 7;
        const int s   = sid & 15;
        const int row = row0 + rl;
        const int l   = s >> 2;
        const int wl  = (l == 0) ? 100 : (l == 1) ? 50 : (l == 2) ? 25 : 13;
        const int st  = (l == 0) ? 0 : (l == 1) ? 10000 : (l == 2) ? 12500 : 13125;
        const float wlf = (float)wl;

        const unsigned short* ol = (const unsigned short*)offlog + (size_t)row * 384;
        const unsigned uoff = *(const unsigned*)(ol + h * 32 + s * 2);
        const float ox = bf2f(uoff & 0xffffu), oy = bf2f(uoff >> 16);
        const float lg = bf2f(ol[256 + h * 16 + s]);
        const float2 rf = *(const float2*)(refpts + (size_t)row * 8 + l * 2);

        // softmax over the 16 lanes of this (row, h)
        float m = lg;
        #pragma unroll
        for (int o = 8; o > 0; o >>= 1) m = fmaxf(m, __shfl_xor(m, o, 16));
        const float e = __expf(lg - m);
        float ssum = e;
        #pragma unroll
        for (int o = 8; o > 0; o >>= 1) ssum += __shfl_xor(ssum, o, 16);
        const float a = e / ssum;

        const float x = fmaf(rf.x, wlf, ox) - 0.5f;
        const float y = fmaf(rf.y, wlf, oy) - 0.5f;
        const float x0f = floorf(x), y0f = floorf(y);
        const int   x0 = (int)x0f, y0 = (int)y0f;
        const float wx1 = x - x0f, wx0 = 1.f - wx1;
        const float wy1 = y - y0f, wy0 = 1.f - wy1;
        const bool xv0 = (unsigned)x0       < (unsigned)wl;
        const bool xv1 = (unsigned)(x0 + 1) < (unsigned)wl;
        const bool yv0 = (unsigned)y0       < (unsigned)wl;
        const bool yv1 = (unsigned)(y0 + 1) < (unsigned)wl;
        const float ax0 = a * wx0, ax1 = a * wx1;
        float w00 = ax0 * wy0, w10 = ax1 * wy0;
        float w01 = ax0 * wy1, w11 = ax1 * wy1;
        w00 = (xv0 && yv0) ? w00 : 0.f;
        w10 = (xv1 && yv0) ? w10 : 0.f;
        w01 = (xv0 && yv1) ? w01 : 0.f;
        w11 = (xv1 && yv1) ? w11 : 0.f;
        const int cx0 = min(max(x0, 0), wl - 1);
        const int cx1 = min(max(x0 + 1, 0), wl - 1);
        const int cy0 = min(max(y0, 0), wl - 1);
        const int cy1 = min(max(y0 + 1, 0), wl - 1);
        const int r0b = (st + cy0 * wl) * 64;   // byte offsets into head plane
        const int r1b = (st + cy1 * wl) * 64;
        uint4  offs; offs.x = r0b + cx0 * 64; offs.y = r0b + cx1 * 64;
                     offs.z = r1b + cx0 * 64; offs.w = r1b + cx1 * 64;
        float4 wv4;  wv4.x = w00; wv4.y = w10; wv4.z = w01; wv4.w = w11;
        char* pe = &params[rl][s][h * 32];
        *(uint4*)pe         = offs;
        *(float4*)(pe + 16) = wv4;
    }
    __syncthreads();

    // ---------------- phase 2 ----------------
    const int rl  = t >> 6;
    const int h   = (t >> 3) & 7;
    const int c4  = t & 7;
    const int row = row0 + rl;
    const int b   = (row >= LQ) ? 1 : 0;
    const char* vbase = (const char*)vhm + ((size_t)((b << 3) + h) * LV) * 64 + c4 * 8;

    float a0 = 0.f, a1 = 0.f, a2 = 0.f, a3 = 0.f;

    #pragma unroll
    for (int sq = 0; sq < 4; ++sq) {
        uint4  of[4]; float4 w[4];
        #pragma unroll
        for (int i = 0; i < 4; ++i) {
            const char* pe = &params[rl][sq * 4 + i][h * 32];
            of[i] = *(const uint4*)pe;
            w[i]  = *(const float4*)(pe + 16);
        }
        uint2 q0[4], q1[4], q2[4], q3[4];
        #pragma unroll
        for (int i = 0; i < 4; ++i) {
            q0[i] = *(const uint2*)(vbase + of[i].x);
            q1[i] = *(const uint2*)(vbase + of[i].y);
            q2[i] = *(const uint2*)(vbase + of[i].z);
            q3[i] = *(const uint2*)(vbase + of[i].w);
        }
        #pragma unroll
        for (int i = 0; i < 4; ++i) {
            union { unsigned u; float f; } lo, hi;
            lo.u = q0[i].x << 16;          a0 = fmaf(lo.f, w[i].x, a0);
            hi.u = q0[i].x & 0xffff0000u;  a1 = fmaf(hi.f, w[i].x, a1);
            lo.u = q0[i].y << 16;          a2 = fmaf(lo.f, w[i].x, a2);
            hi.u = q0[i].y & 0xffff0000u;  a3 = fmaf(hi.f, w[i].x, a3);
            lo.u = q1[i].x << 16;          a0 = fmaf(lo.f, w[i].y, a0);
            hi.u = q1[i].x & 0xffff0000u;  a1 = fmaf(hi.f, w[i].y, a1);
            lo.u = q1[i].y << 16;          a2 = fmaf(lo.f, w[i].y, a2);
            hi.u = q1[i].y & 0xffff0000u;  a3 = fmaf(hi.f, w[i].y, a3);
            lo.u = q2[i].x << 16;          a0 = fmaf(lo.f, w[i].z, a0);
            hi.u = q2[i].x & 0xffff0000u;  a1 = fmaf(hi.f, w[i].z, a1);
            lo.u = q2[i].y << 16;          a2 = fmaf(lo.f, w[i].z, a2);
            hi.u = q2[i].y & 0xffff0000u;  a3 = fmaf(hi.f, w[i].z, a3);
            lo.u = q3[i].x << 16;          a0 = fmaf(lo.f, w[i].w, a0);
            hi.u = q3[i].x & 0xffff0000u;  a1 = fmaf(hi.f, w[i].w, a1);
            lo.u = q3[i].y << 16;          a2 = fmaf(lo.f, w[i].w, a2);
            hi.u = q3[i].y & 0xffff0000u;  a3 = fmaf(hi.f, w[i].w, a3);
        }
    }

    uint2 o;
    o.x = (unsigned)f2bf(a0) | ((unsigned)f2bf(a1) << 16);
    o.y = (unsigned)f2bf(a2) | ((unsigned)f2bf(a3) << 16);
    *(uint2*)((unsigned short*)sampled + (size_t)row * 256 + h * 32 + c4 * 4) = o;
}

extern "C" void kernel_launch(void* const* d_in, const int* in_sizes, int n_in,
                              void* d_out, int out_size, void* d_ws, size_t ws_size,
                              hipStream_t stream)
{
    const float* query  = (const float*)d_in[0];
    const float* refpts = (const float*)d_in[1];
    const float* value  = (const float*)d_in[2];
    const float* Woff   = (const float*)d_in[4];
    const float* boff   = (const float*)d_in[5];
    const float* Wattn  = (const float*)d_in[6];
    const float* battn  = (const float*)d_in[7];
    const float* Wv     = (const float*)d_in[8];
    const float* bv     = (const float*)d_in[9];
    const float* Wout   = (const float*)d_in[10];
    const float* bout   = (const float*)d_in[11];
    float* out = (float*)d_out;

    // workspace (bf16 elements): ~61.7 MB total.
    // vbf is reused as `sampled` (vbf consumed by gemm_vq before ms_sample writes).
    constexpr size_t SZ_VHM = (size_t)2 * 8 * LV * 32;      // 6,806,528
    constexpr size_t SZ_OFF = (size_t)NROWS * 384;          // 10,209,792
    constexpr size_t SZ_ROW = (size_t)NROWS * 256;          // 6,806,528
    __hip_bfloat16* ws      = (__hip_bfloat16*)d_ws;
    __hip_bfloat16* vhm     = ws;
    __hip_bfloat16* offlog  = vhm + SZ_VHM;
    __hip_bfloat16* vbf     = offlog + SZ_OFF;              // then: sampled
    __hip_bfloat16* qbf     = vbf + SZ_ROW;
    __hip_bfloat16* WTf     = qbf + SZ_ROW;                 // 896*256
    __hip_bfloat16* sampled = vbf;

    const int cblk = (int)(((size_t)NROWS * 256 / 8 + 255) / 256);  // 3324 (guarded)
    const int gblk = (NROWS + 63) / 64;              // 416 blocks x 4 rt/block
    const int sblk = NROWS / 4;                      // 6647 (exact)

    hipLaunchKernelGGL(prep_weights, dim3(896), dim3(256), 0, stream,
                       Wv, Woff, Wattn, Wout, WTf);
    hipLaunchKernelGGL(conv_bf16, dim3(cblk, 2), dim3(256), 0, stream,
                       value, query, vbf, qbf);
    hipLaunchKernelGGL(gemm_vq, dim3(gblk, 3), dim3(256), 0, stream,
                       vbf, qbf, WTf, bv, boff, battn, vhm, offlog, NROWS);
    hipLaunchKernelGGL(ms_sample, dim3(sblk), dim3(256), 0, stream,
                       vhm, offlog, refpts, sampled);
    hipLaunchKernelGGL(gemm_out_k, dim3(gblk), dim3(256), 0, stream,
                       sampled, WTf, bout, out, NROWS);
}

// Round 11
// 111.870 us; speedup vs baseline: 1.3824x; 1.3824x over previous
//
#include <hip/hip_runtime.h>
#include <hip/hip_bf16.h>
#include <math.h>

// Deformable DETR multi-scale deformable attention — MI355X (gfx950)
// B=2, Lq=Lv=13294, D=256, H=8, HD=32, L=4, P=4
// Levels (square): 100,50,25,13  starts {0,10000,12500,13125}
// R11 = R7's staged GEMM stack (best measured) + ms_sample v7 (best measured).

namespace {
constexpr int LQ    = 13294;
constexpr int LV    = 13294;
constexpr int NROWS = 2 * LQ;   // 26588
}

typedef __attribute__((ext_vector_type(8))) short short8;   // 8 x bf16
typedef __attribute__((ext_vector_type(4))) float f32x4;    // MFMA accumulator

__device__ inline float bf2f(unsigned u16) {
    union { unsigned u; float f; } c; c.u = u16 << 16; return c.f;
}
__device__ inline unsigned short f2bf(float f) {
    __hip_bfloat16 h = __float2bfloat16(f);
    return *reinterpret_cast<unsigned short*>(&h);
}

// ---------------------------------------------------------------------------
// Weight prep, fragment-major: WTf[ctile][kc][lane][8] bf16 over the
// concatenated [Wv^T|Woff^T|Wattn^T|Wout^T] (896 cols = 56 ctiles).
// ---------------------------------------------------------------------------
__global__ __launch_bounds__(256) void prep_weights(
    const float* __restrict__ Wv, const float* __restrict__ Woff,
    const float* __restrict__ Wattn, const float* __restrict__ Wout,
    __hip_bfloat16* __restrict__ WTf)
{
    const int c = blockIdx.x, k = threadIdx.x;
    float v;
    if (c < 256)      v = Wv[k * 256 + c];
    else if (c < 512) v = Woff[k * 256 + (c - 256)];
    else if (c < 640) v = Wattn[k * 128 + (c - 512)];
    else              v = Wout[k * 256 + (c - 640)];
    const int lane = (c & 15) | (((k >> 3) & 3) << 4);
    const size_t dst = ((size_t)((c >> 4) * 8 + (k >> 5)) * 64 + lane) * 8 + (k & 7);
    WTf[dst] = __float2bfloat16(v);
}

// ---------------------------------------------------------------------------
// GEMM core (R6/R7 structure): 64 rows/block staged in LDS, RT=4 row-tiles,
// fragment-major B (coalesced 1KB loads, L2-resident).
// ---------------------------------------------------------------------------
template<int NT, int OUTMODE, bool A_FP32>
__device__ __forceinline__ void gemm_core(
    short (*As)[264], const void* __restrict__ Xv,
    const __hip_bfloat16* __restrict__ WTf, int ct0,
    const float* __restrict__ bias, void* __restrict__ Yv,
    int ldY, int coloff, int M, int bx)
{
    const int t  = threadIdx.x;
    const int r0 = bx * 64;

    if (A_FP32) {
        const float* X = (const float*)Xv;
        #pragma unroll
        for (int i = 0; i < 16; ++i) {
            const int f4 = i * 256 + t;          // 4096 float4s
            int row = r0 + (f4 >> 6);
            if (row >= M) row = M - 1;
            const int col4 = f4 & 63;
            const float4 u = *(const float4*)(X + (size_t)row * 256 + col4 * 4);
            union { unsigned short us[4]; uint2 v; } p;
            p.us[0] = f2bf(u.x); p.us[1] = f2bf(u.y);
            p.us[2] = f2bf(u.z); p.us[3] = f2bf(u.w);
            *(uint2*)(&As[f4 >> 6][col4 * 4]) = p.v;
        }
    } else {
        const __hip_bfloat16* X = (const __hip_bfloat16*)Xv;
        #pragma unroll
        for (int i = 0; i < 8; ++i) {
            const int f8 = i * 256 + t;          // 2048 16B-chunks
            int row = r0 + (f8 >> 5);
            if (row >= M) row = M - 1;
            const int c16 = f8 & 31;
            *(short8*)(&As[f8 >> 5][c16 * 8]) =
                *(const short8*)(X + (size_t)row * 256 + c16 * 8);
        }
    }
    __syncthreads();

    const int lane = t & 63;
    const int wv   = t >> 6;
    const int r16  = lane & 15;
    const int koff = (lane >> 4) * 8;

    f32x4 acc[4][NT];
    #pragma unroll
    for (int rt = 0; rt < 4; ++rt)
        #pragma unroll
        for (int nt = 0; nt < NT; ++nt)
            #pragma unroll
            for (int j = 0; j < 4; ++j) acc[rt][nt][j] = 0.f;

    #pragma unroll
    for (int kc = 0; kc < 8; ++kc) {
        short8 a[4];
        #pragma unroll
        for (int rt = 0; rt < 4; ++rt)
            a[rt] = *(const short8*)(&As[rt * 16 + r16][kc * 32 + koff]);
        #pragma unroll
        for (int nt = 0; nt < NT; ++nt) {
            const int ct = ct0 + wv * NT + nt;
            const short8 bfr =
                *(const short8*)(WTf + ((size_t)(ct * 8 + kc) * 64 + lane) * 8);
            #pragma unroll
            for (int rt = 0; rt < 4; ++rt)
                acc[rt][nt] = __builtin_amdgcn_mfma_f32_16x16x32_bf16(
                    a[rt], bfr, acc[rt][nt], 0, 0, 0);
        }
    }

    const int orow = (lane >> 4) * 4;
    #pragma unroll
    for (int rt = 0; rt < 4; ++rt)
    #pragma unroll
    for (int nt = 0; nt < NT; ++nt) {
        const int lcol = wv * (NT * 16) + nt * 16 + r16;
        const float bb = bias[lcol];
        #pragma unroll
        for (int j = 0; j < 4; ++j) {
            const int rr = r0 + rt * 16 + orow + j;
            if (rr < M) {
                const float v = acc[rt][nt][j] + bb;
                if (OUTMODE == 0) {
                    ((float*)Yv)[(size_t)rr * ldY + coloff + lcol] = v;
                } else if (OUTMODE == 1) {
                    ((__hip_bfloat16*)Yv)[(size_t)rr * ldY + coloff + lcol] =
                        __float2bfloat16(v);
                } else {
                    const int b  = (rr >= LQ) ? 1 : 0;
                    const int lv = rr - b * LQ;
                    const int h  = lcol >> 5, cc = lcol & 31;
                    ((__hip_bfloat16*)Yv)[(((size_t)(b * 8 + h)) * LV + lv) * 32 + cc] =
                        __float2bfloat16(v);
                }
            }
        }
    }
}

// fused: y=0 value->vhm (N=256) | y=1 query->offsets (N=256) | y=2 query->logits (N=128)
__global__ __launch_bounds__(256, 2) void gemm_vq(
    const float* __restrict__ value, const float* __restrict__ query,
    const __hip_bfloat16* __restrict__ WTf,
    const float* __restrict__ bv, const float* __restrict__ boff,
    const float* __restrict__ battn,
    __hip_bfloat16* __restrict__ vhm, __hip_bfloat16* __restrict__ offlog, int M)
{
    __shared__ short As[64][264];
    if (blockIdx.y == 0)
        gemm_core<4, 2, true>(As, value, WTf, 0,  bv,    vhm,    0,   0,   M, blockIdx.x);
    else if (blockIdx.y == 1)
        gemm_core<4, 1, true>(As, query, WTf, 16, boff,  offlog, 384, 0,   M, blockIdx.x);
    else
        gemm_core<2, 1, true>(As, query, WTf, 32, battn, offlog, 384, 256, M, blockIdx.x);
}

__global__ __launch_bounds__(256, 2) void gemm_out_k(
    const __hip_bfloat16* __restrict__ sampled, const __hip_bfloat16* __restrict__ WTf,
    const float* __restrict__ bout, float* __restrict__ out, int M)
{
    __shared__ short As[64][264];
    gemm_core<4, 0, false>(As, sampled, WTf, 40, bout, out, 256, 0, M, blockIdx.x);
}

// ---------------------------------------------------------------------------
// ms_sample v7 (measured 62.4 µs): 4 rows x all heads per block,
// 4-sample batched gathers.
// ---------------------------------------------------------------------------
__global__ __launch_bounds__(256) void ms_sample(
    const __hip_bfloat16* __restrict__ vhm, const __hip_bfloat16* __restrict__ offlog,
    const float* __restrict__ refpts, __hip_bfloat16* __restrict__ sampled)
{
    __shared__ char params[4][16][304];

    const int t    = threadIdx.x;
    const int row0 = blockIdx.x * 4;

    // ---------------- phase 1 ----------------
    #pragma unroll
    for (int it = 0; it < 2; ++it) {
        const int sid = it * 256 + t;
        const int rl  = sid >> 7;
        const int h   = (sid >> 4) & 7;
        const int s   = sid & 15;
        const int row = row0 + rl;
        const int l   = s >> 2;
        const int wl  = (l == 0) ? 100 : (l == 1) ? 50 : (l == 2) ? 25 : 13;
        const int st  = (l == 0) ? 0 : (l == 1) ? 10000 : (l == 2) ? 12500 : 13125;
        const float wlf = (float)wl;

        const unsigned short* ol = (const unsigned short*)offlog + (size_t)row * 384;
        const unsigned uoff = *(const unsigned*)(ol + h * 32 + s * 2);
        const float ox = bf2f(uoff & 0xffffu), oy = bf2f(uoff >> 16);
        const float lg = bf2f(ol[256 + h * 16 + s]);
        const float2 rf = *(const float2*)(refpts + (size_t)row * 8 + l * 2);

        // softmax over the 16 lanes of this (row, h)
        float m = lg;
        #pragma unroll
        for (int o = 8; o > 0; o >>= 1) m = fmaxf(m, __shfl_xor(m, o, 16));
        const float e = __expf(lg - m);
        float ssum = e;
        #pragma unroll
        for (int o = 8; o > 0; o >>= 1) ssum += __shfl_xor(ssum, o, 16);
        const float a = e / ssum;

        const float x = fmaf(rf.x, wlf, ox) - 0.5f;
        const float y = fmaf(rf.y, wlf, oy) - 0.5f;
        const float x0f = floorf(x), y0f = floorf(y);
        const int   x0 = (int)x0f, y0 = (int)y0f;
        const float wx1 = x - x0f, wx0 = 1.f - wx1;
        const float wy1 = y - y0f, wy0 = 1.f - wy1;
        const bool xv0 = (unsigned)x0       < (unsigned)wl;
        const bool xv1 = (unsigned)(x0 + 1) < (unsigned)wl;
        const bool yv0 = (unsigned)y0       < (unsigned)wl;
        const bool yv1 = (unsigned)(y0 + 1) < (unsigned)wl;
        const float ax0 = a * wx0, ax1 = a * wx1;
        float w00 = ax0 * wy0, w10 = ax1 * wy0;
        float w01 = ax0 * wy1, w11 = ax1 * wy1;
        w00 = (xv0 && yv0) ? w00 : 0.f;
        w10 = (xv1 && yv0) ? w10 : 0.f;
        w01 = (xv0 && yv1) ? w01 : 0.f;
        w11 = (xv1 && yv1) ? w11 : 0.f;
        const int cx0 = min(max(x0, 0), wl - 1);
        const int cx1 = min(max(x0 + 1, 0), wl - 1);
        const int cy0 = min(max(y0, 0), wl - 1);
        const int cy1 = min(max(y0 + 1, 0), wl - 1);
        const int r0b = (st + cy0 * wl) * 64;   // byte offsets into head plane
        const int r1b = (st + cy1 * wl) * 64;
        uint4  offs; offs.x = r0b + cx0 * 64; offs.y = r0b + cx1 * 64;
                     offs.z = r1b + cx0 * 64; offs.w = r1b + cx1 * 64;
        float4 wv4;  wv4.x = w00; wv4.y = w10; wv4.z = w01; wv4.w = w11;
        char* pe = &params[rl][s][h * 32];
        *(uint4*)pe         = offs;
        *(float4*)(pe + 16) = wv4;
    }
    __syncthreads();

    // ---------------- phase 2 ----------------
    const int rl  = t >> 6;
    const int h   = (t >> 3) & 7;
    const int c4  = t & 7;
    const int row = row0 + rl;
    const int b   = (row >= LQ) ? 1 : 0;
    const char* vbase = (const char*)vhm + ((size_t)((b << 3) + h) * LV) * 64 + c4 * 8;

    float a0 = 0.f, a1 = 0.f, a2 = 0.f, a3 = 0.f;

    #pragma unroll
    for (int sq = 0; sq < 4; ++sq) {
        uint4  of[4]; float4 w[4];
        #pragma unroll
        for (int i = 0; i < 4; ++i) {
            const char* pe = &params[rl][sq * 4 + i][h * 32];
            of[i] = *(const uint4*)pe;
            w[i]  = *(const float4*)(pe + 16);
        }
        uint2 q0[4], q1[4], q2[4], q3[4];
        #pragma unroll
        for (int i = 0; i < 4; ++i) {
            q0[i] = *(const uint2*)(vbase + of[i].x);
            q1[i] = *(const uint2*)(vbase + of[i].y);
            q2[i] = *(const uint2*)(vbase + of[i].z);
            q3[i] = *(const uint2*)(vbase + of[i].w);
        }
        #pragma unroll
        for (int i = 0; i < 4; ++i) {
            union { unsigned u; float f; } lo, hi;
            lo.u = q0[i].x << 16;          a0 = fmaf(lo.f, w[i].x, a0);
            hi.u = q0[i].x & 0xffff0000u;  a1 = fmaf(hi.f, w[i].x, a1);
            lo.u = q0[i].y << 16;          a2 = fmaf(lo.f, w[i].x, a2);
            hi.u = q0[i].y & 0xffff0000u;  a3 = fmaf(hi.f, w[i].x, a3);
            lo.u = q1[i].x << 16;          a0 = fmaf(lo.f, w[i].y, a0);
            hi.u = q1[i].x & 0xffff0000u;  a1 = fmaf(hi.f, w[i].y, a1);
            lo.u = q1[i].y << 16;          a2 = fmaf(lo.f, w[i].y, a2);
            hi.u = q1[i].y & 0xffff0000u;  a3 = fmaf(hi.f, w[i].y, a3);
            lo.u = q2[i].x << 16;          a0 = fmaf(lo.f, w[i].z, a0);
            hi.u = q2[i].x & 0xffff0000u;  a1 = fmaf(hi.f, w[i].z, a1);
            lo.u = q2[i].y << 16;          a2 = fmaf(lo.f, w[i].z, a2);
            hi.u = q2[i].y & 0xffff0000u;  a3 = fmaf(hi.f, w[i].z, a3);
            lo.u = q3[i].x << 16;          a0 = fmaf(lo.f, w[i].w, a0);
            hi.u = q3[i].x & 0xffff0000u;  a1 = fmaf(hi.f, w[i].w, a1);
            lo.u = q3[i].y << 16;          a2 = fmaf(lo.f, w[i].w, a2);
            hi.u = q3[i].y & 0xffff0000u;  a3 = fmaf(hi.f, w[i].w, a3);
        }
    }

    uint2 o;
    o.x = (unsigned)f2bf(a0) | ((unsigned)f2bf(a1) << 16);
    o.y = (unsigned)f2bf(a2) | ((unsigned)f2bf(a3) << 16);
    *(uint2*)((unsigned short*)sampled + (size_t)row * 256 + h * 32 + c4 * 4) = o;
}

extern "C" void kernel_launch(void* const* d_in, const int* in_sizes, int n_in,
                              void* d_out, int out_size, void* d_ws, size_t ws_size,
                              hipStream_t stream)
{
    const float* query  = (const float*)d_in[0];
    const float* refpts = (const float*)d_in[1];
    const float* value  = (const float*)d_in[2];
    const float* Woff   = (const float*)d_in[4];
    const float* boff   = (const float*)d_in[5];
    const float* Wattn  = (const float*)d_in[6];
    const float* battn  = (const float*)d_in[7];
    const float* Wv     = (const float*)d_in[8];
    const float* bv     = (const float*)d_in[9];
    const float* Wout   = (const float*)d_in[10];
    const float* bout   = (const float*)d_in[11];
    float* out = (float*)d_out;

    // workspace (bf16 elements): 48.1 MB total
    constexpr size_t SZ_VHM = (size_t)2 * 8 * LV * 32;      // 6,806,528
    constexpr size_t SZ_OFF = (size_t)NROWS * 384;          // 10,209,792
    constexpr size_t SZ_ROW = (size_t)NROWS * 256;          // 6,806,528
    __hip_bfloat16* ws      = (__hip_bfloat16*)d_ws;
    __hip_bfloat16* vhm     = ws;
    __hip_bfloat16* offlog  = vhm + SZ_VHM;
    __hip_bfloat16* sampled = offlog + SZ_OFF;
    __hip_bfloat16* WTf     = sampled + SZ_ROW;             // 896*256

    const int gblk = (NROWS + 63) / 64;   // 416
    const int sblk = NROWS / 4;           // 6647 (exact)

    hipLaunchKernelGGL(prep_weights, dim3(896), dim3(256), 0, stream,
                       Wv, Woff, Wattn, Wout, WTf);
    hipLaunchKernelGGL(gemm_vq, dim3(gblk, 3), dim3(256), 0, stream,
                       value, query, WTf, bv, boff, battn, vhm, offlog, NROWS);
    hipLaunchKernelGGL(ms_sample, dim3(sblk), dim3(256), 0, stream,
                       vhm, offlog, refpts, sampled);
    hipLaunchKernelGGL(gemm_out_k, dim3(gblk), dim3(256), 0, stream,
                       sampled, WTf, bout, out, NROWS);
}